// Round 1
// baseline (1427.766 us; speedup 1.0000x reference)
//
#include <hip/hip_runtime.h>
#include <hip/hip_bf16.h>
#include <math.h>

#define N_NODES   100000
#define N_EDGES   1200000
#define EO        64
#define HID       256
#define NOUT      128

// ---------------- init workspace ----------------
__global__ void init_k(float* __restrict__ out1, float* __restrict__ out2,
                       unsigned* __restrict__ cnt) {
    int i = blockIdx.x * 256 + threadIdx.x;
    if (i < N_NODES * EO) {
        out1[i] = 0.0f;
        ((unsigned*)out2)[i] = 0xFF800000u;  // -inf
    }
    if (i < N_NODES) cnt[i] = 0u;
}

// float atomic max via signed/unsigned ordering trick (init must be -inf)
__device__ __forceinline__ void atomicMaxF(float* a, float v) {
    if (v >= 0.0f) atomicMax((int*)a, __float_as_int(v));
    else           atomicMin((unsigned int*)a, __float_as_uint(v));
}

// ---------------- scatter: one thread per (edge, feature) ----------------
__global__ void scatter_k(const float* __restrict__ ea, const int* __restrict__ ei,
                          float* __restrict__ out1, float* __restrict__ out2,
                          unsigned* __restrict__ cnt) {
    int idx = blockIdx.x * 256 + threadIdx.x;     // < 76.8M, fits in int
    int e = idx >> 6;
    int f = idx & 63;
    if (e >= N_EDGES) return;
    int col = ei[N_EDGES + e];                    // second row of edge_index
    float v = ea[idx];
    atomicAdd(&out1[col * EO + f], v);
    atomicMaxF(&out2[col * EO + f], v);
    if (f == 0) atomicAdd(&cnt[col], 1u);
}

// ---------------- fused MLP: 32 rows per block ----------------
// feat = [out1 | out2(gated) | out1/max(cnt,1) | u[batch]]  (193 cols)
// h = gelu(feat @ W1 + b1)   (256)   -> out = h @ W2 + b2   (128)
#define TILE_R 32
#define FSTRIDE 196   // 193 padded to mult of 4 for aligned float4 LDS reads

__launch_bounds__(256)
__global__ void mlp_k(const float* __restrict__ out1, const float* __restrict__ out2,
                      const unsigned* __restrict__ cnt,
                      const float* __restrict__ u, const int* __restrict__ batch,
                      const float* __restrict__ W1, const float* __restrict__ b1,
                      const float* __restrict__ W2, const float* __restrict__ b2,
                      float* __restrict__ out) {
    __shared__ float smem[TILE_R * HID];   // 32*256 floats = 32 KB; feat (32*196) aliases it

    float* feat = smem;   // stride FSTRIDE
    float* h    = smem;   // stride HID (after barrier)

    const int row_base = blockIdx.x * TILE_R;

    // ---- stage feat into LDS ----
    for (int i = threadIdx.x; i < TILE_R * 193; i += 256) {
        int r = i / 193;
        int k = i - r * 193;
        int row = row_base + r;
        float v;
        if (k < 64) {
            v = out1[row * EO + k];
        } else if (k < 128) {
            v = (cnt[row] > 0u) ? out2[row * EO + (k - 64)] : 0.0f;
        } else if (k < 192) {
            float c = (float)cnt[row];
            v = out1[row * EO + (k - 128)] / fmaxf(c, 1.0f);
        } else {
            v = u[batch[row]];
        }
        feat[r * FSTRIDE + k] = v;
    }
    __syncthreads();

    // ---- GEMM1 + GELU: thread j owns hidden column j, 32 rows ----
    const int j = threadIdx.x;
    const float bj = b1[j];
    float hreg[TILE_R];

    #pragma unroll
    for (int rb = 0; rb < 2; ++rb) {
        float acc[16];
        #pragma unroll
        for (int rr = 0; rr < 16; ++rr) acc[rr] = bj;
        for (int k = 0; k < 192; k += 4) {
            float w0 = W1[(k + 0) * HID + j];
            float w1 = W1[(k + 1) * HID + j];
            float w2 = W1[(k + 2) * HID + j];
            float w3 = W1[(k + 3) * HID + j];
            #pragma unroll
            for (int rr = 0; rr < 16; ++rr) {
                const float4 f4 = *(const float4*)&feat[(rb * 16 + rr) * FSTRIDE + k];
                acc[rr] += f4.x * w0 + f4.y * w1 + f4.z * w2 + f4.w * w3;
            }
        }
        float wl = W1[192 * HID + j];
        #pragma unroll
        for (int rr = 0; rr < 16; ++rr)
            acc[rr] += feat[(rb * 16 + rr) * FSTRIDE + 192] * wl;
        #pragma unroll
        for (int rr = 0; rr < 16; ++rr) {
            float t = acc[rr];
            hreg[rb * 16 + rr] = 0.5f * t * (1.0f + erff(t * 0.70710678118654752f));
        }
    }

    __syncthreads();   // feat fully consumed
    #pragma unroll
    for (int rr = 0; rr < TILE_R; ++rr) h[rr * HID + j] = hreg[rr];
    __syncthreads();

    // ---- GEMM2: thread (n = tid&127) owns out column n; rows split in 2 groups ----
    const int n  = threadIdx.x & 127;
    const int rg = threadIdx.x >> 7;   // 0 or 1 -> rows [0,16) / [16,32)
    const float bn = b2[n];
    float acc2[16];
    #pragma unroll
    for (int rr = 0; rr < 16; ++rr) acc2[rr] = bn;
    for (int k = 0; k < HID; k += 4) {
        float w0 = W2[(k + 0) * NOUT + n];
        float w1 = W2[(k + 1) * NOUT + n];
        float w2 = W2[(k + 2) * NOUT + n];
        float w3 = W2[(k + 3) * NOUT + n];
        #pragma unroll
        for (int rr = 0; rr < 16; ++rr) {
            const float4 h4 = *(const float4*)&h[(rg * 16 + rr) * HID + k];
            acc2[rr] += h4.x * w0 + h4.y * w1 + h4.z * w2 + h4.w * w3;
        }
    }
    const int row0 = row_base + rg * 16;
    #pragma unroll
    for (int rr = 0; rr < 16; ++rr)
        out[(row0 + rr) * NOUT + n] = acc2[rr];
}

extern "C" void kernel_launch(void* const* d_in, const int* in_sizes, int n_in,
                              void* d_out, int out_size, void* d_ws, size_t ws_size,
                              hipStream_t stream) {
    // inputs: x, edge_index, edge_attr, u, batch, W1, b1, W2, b2
    const int*   ei    = (const int*)d_in[1];
    const float* ea    = (const float*)d_in[2];
    const float* u     = (const float*)d_in[3];
    const int*   batch = (const int*)d_in[4];
    const float* W1    = (const float*)d_in[5];
    const float* b1    = (const float*)d_in[6];
    const float* W2    = (const float*)d_in[7];
    const float* b2    = (const float*)d_in[8];
    float* out = (float*)d_out;

    float*    out1 = (float*)d_ws;
    float*    out2 = out1 + (size_t)N_NODES * EO;
    unsigned* cnt  = (unsigned*)(out2 + (size_t)N_NODES * EO);

    init_k<<<(N_NODES * EO + 255) / 256, 256, 0, stream>>>(out1, out2, cnt);
    scatter_k<<<(N_EDGES * EO + 255) / 256, 256, 0, stream>>>(ea, ei, out1, out2, cnt);
    mlp_k<<<N_NODES / TILE_R, 256, 0, stream>>>(out1, out2, cnt, u, batch,
                                                W1, b1, W2, b2, out);
}

// Round 2
// 1091.008 us; speedup vs baseline: 1.3087x; 1.3087x over previous
//
#include <hip/hip_runtime.h>
#include <hip/hip_bf16.h>
#include <math.h>

#define N_NODES 100000
#define N_EDGES 1200000
#define EO      64
#define HID     256
#define NOUT    128
#define KP      224     // 193 padded to 7*32 for K-loop
#define TILE_R  64
#define HSTR    264     // h LDS stride (bf16 elems), padded vs 256

typedef __attribute__((ext_vector_type(8))) short bf16x8;
typedef __attribute__((ext_vector_type(4))) float f32x4;

__device__ __forceinline__ short f2bf(float x) {
    __hip_bfloat16 h = __float2bfloat16(x);
    return *reinterpret_cast<short*>(&h);
}

// ---- weight transpose + bf16 convert: W1T[n][k] (k<193 else 0), W2T[n][k] ----
__global__ void prep_k(const float* __restrict__ W1, const float* __restrict__ W2,
                       short* __restrict__ W1T, short* __restrict__ W2T) {
    int i = blockIdx.x * 256 + threadIdx.x;
    if (i < HID * KP) {
        int n = i / KP, k = i - n * KP;
        W1T[i] = (k < 193) ? f2bf(W1[k * HID + n]) : (short)0;
    } else {
        int j = i - HID * KP;
        if (j < NOUT * HID) {
            int n = j / HID, k = j - n * HID;
            W2T[j] = f2bf(W2[k * NOUT + n]);
        }
    }
}

// ---- CSR build ----
__global__ void hist_k(const int* __restrict__ ei, unsigned* __restrict__ hist) {
    int e = blockIdx.x * 256 + threadIdx.x;
    if (e < N_EDGES) atomicAdd(&hist[ei[N_EDGES + e]], 1u);
}

__global__ void scan_part_k(unsigned* __restrict__ off, unsigned* __restrict__ bsum) {
    __shared__ unsigned s[256];
    int t = threadIdx.x, i = blockIdx.x * 256 + t;
    unsigned v = (i < N_NODES) ? off[i] : 0u;
    s[t] = v; __syncthreads();
    for (int d = 1; d < 256; d <<= 1) {
        unsigned x = (t >= d) ? s[t - d] : 0u; __syncthreads();
        s[t] += x; __syncthreads();
    }
    if (i < N_NODES) off[i] = s[t] - v;       // block-local exclusive
    if (t == 255) bsum[blockIdx.x] = s[255];
}

__global__ void scan_top_k(const unsigned* __restrict__ bsum, unsigned* __restrict__ boff, int nb) {
    __shared__ unsigned s[512];
    int t = threadIdx.x;
    unsigned v = (t < nb) ? bsum[t] : 0u;
    s[t] = v; __syncthreads();
    for (int d = 1; d < 512; d <<= 1) {
        unsigned x = (t >= d) ? s[t - d] : 0u; __syncthreads();
        s[t] += x; __syncthreads();
    }
    boff[t] = s[t] - v;
}

__global__ void scan_add_k(unsigned* __restrict__ off, const unsigned* __restrict__ boff,
                           unsigned* __restrict__ cursor) {
    int i = blockIdx.x * 256 + threadIdx.x;
    if (i < N_NODES) {
        unsigned o = off[i] + boff[blockIdx.x];
        off[i] = o; cursor[i] = o;
    }
}

__global__ void place_k(const int* __restrict__ ei, unsigned* __restrict__ cursor,
                        unsigned* __restrict__ perm) {
    int e = blockIdx.x * 256 + threadIdx.x;
    if (e < N_EDGES) {
        int c = ei[N_EDGES + e];
        unsigned p = atomicAdd(&cursor[c], 1u);
        perm[p] = (unsigned)e;
    }
}

// ---- fused gather + MLP (bf16 MFMA, fp32 accum) ----
__launch_bounds__(256)
__global__ void fused_k(const unsigned* __restrict__ off, const unsigned* __restrict__ perm,
                        const float* __restrict__ ea, const float* __restrict__ u,
                        const int* __restrict__ batch,
                        const short* __restrict__ W1T, const short* __restrict__ W2T,
                        const float* __restrict__ b1, const float* __restrict__ b2,
                        float* __restrict__ out) {
    __shared__ short smem[TILE_R * HSTR];  // 33 KB; feat (stride KP) aliases h (stride HSTR)

    const int tid = threadIdx.x;
    const int w = tid >> 6;
    const int lane = tid & 63;
    const int row_base = blockIdx.x * TILE_R;

    // ---- gather: wave w handles 16 nodes, lane = feature ----
    for (int i = 0; i < 16; ++i) {
        const int rl = w * 16 + i;
        const int n = row_base + rl;
        short* frow = &smem[rl * KP];
        if (n < N_NODES) {
            const int s0 = (int)off[n];
            const int e_end = (n + 1 < N_NODES) ? (int)off[n + 1] : N_EDGES;
            const int deg = e_end - s0;
            float sum = 0.0f, mx = -INFINITY;
            for (int p = s0; p < e_end; ++p) {
                const int e = (int)perm[p];
                const float v = ea[(size_t)e * EO + lane];
                sum += v; mx = fmaxf(mx, v);
            }
            frow[lane]          = f2bf(sum);
            frow[EO + lane]     = f2bf(deg > 0 ? mx : 0.0f);
            frow[2 * EO + lane] = f2bf(sum / fmaxf((float)deg, 1.0f));
            if (lane < 32) frow[192 + lane] = (lane == 0) ? f2bf(u[batch[n]]) : (short)0;
        } else {
            frow[lane] = 0; frow[EO + lane] = 0; frow[2 * EO + lane] = 0;
            if (lane < 32) frow[192 + lane] = 0;
        }
    }
    __syncthreads();

    const int m = lane & 15, q = lane >> 4;
    const f32x4 vzero = {0.0f, 0.0f, 0.0f, 0.0f};

    // ---- GEMM1: 64 x 256, K=224; wave w owns cols [w*64, w*64+64) ----
    f32x4 acc1[4][4];
    #pragma unroll
    for (int a = 0; a < 4; ++a)
        #pragma unroll
        for (int b = 0; b < 4; ++b) acc1[a][b] = vzero;

    for (int kk = 0; kk < 7; ++kk) {
        const int k0 = kk * 32;
        bf16x8 afr[4];
        #pragma unroll
        for (int mt = 0; mt < 4; ++mt)
            afr[mt] = *(const bf16x8*)&smem[(mt * 16 + m) * KP + k0 + q * 8];
        #pragma unroll
        for (int ct = 0; ct < 4; ++ct) {
            const int col = w * 64 + ct * 16 + m;
            bf16x8 bfr = *(const bf16x8*)&W1T[col * KP + k0 + q * 8];
            #pragma unroll
            for (int mt = 0; mt < 4; ++mt)
                acc1[mt][ct] = __builtin_amdgcn_mfma_f32_16x16x32_bf16(afr[mt], bfr, acc1[mt][ct], 0, 0, 0);
        }
    }
    __syncthreads();   // feat fully consumed; smem becomes h

    // epilogue: bias + exact GELU -> h bf16 (stride HSTR)
    #pragma unroll
    for (int ct = 0; ct < 4; ++ct) {
        const int col = w * 64 + ct * 16 + m;
        const float bv = b1[col];
        #pragma unroll
        for (int mt = 0; mt < 4; ++mt) {
            #pragma unroll
            for (int i = 0; i < 4; ++i) {
                float t = acc1[mt][ct][i] + bv;
                t = 0.5f * t * (1.0f + erff(t * 0.70710678118654752f));
                smem[(mt * 16 + q * 4 + i) * HSTR + col] = f2bf(t);
            }
        }
    }
    __syncthreads();

    // ---- GEMM2: 64 x 128, K=256; wave w owns cols [w*32, w*32+32) ----
    f32x4 acc2[4][2];
    #pragma unroll
    for (int a = 0; a < 4; ++a) { acc2[a][0] = vzero; acc2[a][1] = vzero; }

    for (int kk = 0; kk < 8; ++kk) {
        const int k0 = kk * 32;
        bf16x8 afr[4];
        #pragma unroll
        for (int mt = 0; mt < 4; ++mt)
            afr[mt] = *(const bf16x8*)&smem[(mt * 16 + m) * HSTR + k0 + q * 8];
        #pragma unroll
        for (int ct = 0; ct < 2; ++ct) {
            const int col = w * 32 + ct * 16 + m;
            bf16x8 bfr = *(const bf16x8*)&W2T[col * HID + k0 + q * 8];
            #pragma unroll
            for (int mt = 0; mt < 4; ++mt)
                acc2[mt][ct] = __builtin_amdgcn_mfma_f32_16x16x32_bf16(afr[mt], bfr, acc2[mt][ct], 0, 0, 0);
        }
    }

    #pragma unroll
    for (int ct = 0; ct < 2; ++ct) {
        const int col = w * 32 + ct * 16 + m;
        const float bv = b2[col];
        #pragma unroll
        for (int mt = 0; mt < 4; ++mt) {
            #pragma unroll
            for (int i = 0; i < 4; ++i) {
                const int row = row_base + mt * 16 + q * 4 + i;
                if (row < N_NODES) out[(size_t)row * NOUT + col] = acc2[mt][ct][i] + bv;
            }
        }
    }
}

extern "C" void kernel_launch(void* const* d_in, const int* in_sizes, int n_in,
                              void* d_out, int out_size, void* d_ws, size_t ws_size,
                              hipStream_t stream) {
    // inputs: x, edge_index, edge_attr, u, batch, W1, b1, W2, b2
    const int*   ei    = (const int*)d_in[1];
    const float* ea    = (const float*)d_in[2];
    const float* u     = (const float*)d_in[3];
    const int*   batch = (const int*)d_in[4];
    const float* W1    = (const float*)d_in[5];
    const float* b1    = (const float*)d_in[6];
    const float* W2    = (const float*)d_in[7];
    const float* b2    = (const float*)d_in[8];
    float* out = (float*)d_out;

    unsigned* off    = (unsigned*)d_ws;          // N
    unsigned* cursor = off + N_NODES;            // N
    unsigned* perm   = cursor + N_NODES;         // E
    unsigned* bsum   = perm + N_EDGES;           // 512
    unsigned* boff   = bsum + 512;               // 512
    short*    W1T    = (short*)(boff + 512);     // 256*224 bf16
    short*    W2T    = W1T + HID * KP;           // 128*256 bf16

    const int NB = (N_NODES + 255) / 256;        // 391

    hipMemsetAsync(off, 0, (size_t)N_NODES * 4, stream);
    prep_k<<<(HID * KP + NOUT * HID + 255) / 256, 256, 0, stream>>>(W1, W2, W1T, W2T);
    hist_k<<<(N_EDGES + 255) / 256, 256, 0, stream>>>(ei, off);
    scan_part_k<<<NB, 256, 0, stream>>>(off, bsum);
    scan_top_k<<<1, 512, 0, stream>>>(bsum, boff, NB);
    scan_add_k<<<NB, 256, 0, stream>>>(off, boff, cursor);
    place_k<<<(N_EDGES + 255) / 256, 256, 0, stream>>>(ei, cursor, perm);
    fused_k<<<(N_NODES + TILE_R - 1) / TILE_R, 256, 0, stream>>>(
        off, perm, ea, u, batch, W1T, W2T, b1, b2, out);
}

// Round 3
// 772.059 us; speedup vs baseline: 1.8493x; 1.4131x over previous
//
#include <hip/hip_runtime.h>
#include <hip/hip_bf16.h>
#include <math.h>

#define N_NODES 100000
#define N_EDGES 1200000
#define EO      64
#define HID     256
#define NOUT    128
#define KP      224     // 193 padded to 7*32 for K-loop
#define TILE_R  64
#define HSTR    264     // h LDS stride (bf16 elems), padded vs 256

typedef __attribute__((ext_vector_type(8))) short bf16x8;
typedef __attribute__((ext_vector_type(4))) float f32x4;

__device__ __forceinline__ short f2bf(float x) {
    __hip_bfloat16 h = __float2bfloat16(x);
    return *reinterpret_cast<short*>(&h);
}

__device__ __forceinline__ f32x4 max4(f32x4 a, f32x4 b) {
    f32x4 r;
    r.x = fmaxf(a.x, b.x); r.y = fmaxf(a.y, b.y);
    r.z = fmaxf(a.z, b.z); r.w = fmaxf(a.w, b.w);
    return r;
}

// ---- weight transpose + bf16 convert: W1T[n][k] (k<193 else 0), W2T[n][k] ----
__global__ void prep_k(const float* __restrict__ W1, const float* __restrict__ W2,
                       short* __restrict__ W1T, short* __restrict__ W2T) {
    int i = blockIdx.x * 256 + threadIdx.x;
    if (i < HID * KP) {
        int n = i / KP, k = i - n * KP;
        W1T[i] = (k < 193) ? f2bf(W1[k * HID + n]) : (short)0;
    } else {
        int j = i - HID * KP;
        if (j < NOUT * HID) {
            int n = j / HID, k = j - n * HID;
            W2T[j] = f2bf(W2[k * NOUT + n]);
        }
    }
}

// ---- CSR build ----
__global__ void hist_k(const int* __restrict__ ei, unsigned* __restrict__ hist) {
    int e = blockIdx.x * 256 + threadIdx.x;
    if (e < N_EDGES) atomicAdd(&hist[ei[N_EDGES + e]], 1u);
}

__global__ void scan_part_k(unsigned* __restrict__ off, unsigned* __restrict__ bsum) {
    __shared__ unsigned s[256];
    int t = threadIdx.x, i = blockIdx.x * 256 + t;
    unsigned v = (i < N_NODES) ? off[i] : 0u;
    s[t] = v; __syncthreads();
    for (int d = 1; d < 256; d <<= 1) {
        unsigned x = (t >= d) ? s[t - d] : 0u; __syncthreads();
        s[t] += x; __syncthreads();
    }
    if (i < N_NODES) off[i] = s[t] - v;       // block-local exclusive
    if (t == 255) bsum[blockIdx.x] = s[255];
}

__global__ void scan_top_k(const unsigned* __restrict__ bsum, unsigned* __restrict__ boff, int nb) {
    __shared__ unsigned s[512];
    int t = threadIdx.x;
    unsigned v = (t < nb) ? bsum[t] : 0u;
    s[t] = v; __syncthreads();
    for (int d = 1; d < 512; d <<= 1) {
        unsigned x = (t >= d) ? s[t - d] : 0u; __syncthreads();
        s[t] += x; __syncthreads();
    }
    boff[t] = s[t] - v;
}

__global__ void scan_add_k(unsigned* __restrict__ off, const unsigned* __restrict__ boff,
                           unsigned* __restrict__ cursor) {
    int i = blockIdx.x * 256 + threadIdx.x;
    if (i < N_NODES) {
        unsigned o = off[i] + boff[blockIdx.x];
        off[i] = o; cursor[i] = o;
    }
}

__global__ void place_k(const int* __restrict__ ei, unsigned* __restrict__ cursor,
                        unsigned* __restrict__ perm) {
    int e = blockIdx.x * 256 + threadIdx.x;
    if (e < N_EDGES) {
        int c = ei[N_EDGES + e];
        unsigned p = atomicAdd(&cursor[c], 1u);
        perm[p] = (unsigned)e;
    }
}

// ---- fused gather + MLP (bf16 MFMA, fp32 accum) ----
__launch_bounds__(256)
__global__ void fused_k(const unsigned* __restrict__ off, const unsigned* __restrict__ perm,
                        const float* __restrict__ ea, const float* __restrict__ u,
                        const int* __restrict__ batch,
                        const short* __restrict__ W1T, const short* __restrict__ W2T,
                        const float* __restrict__ b1, const float* __restrict__ b2,
                        float* __restrict__ out) {
    __shared__ short smem[TILE_R * HSTR];  // 33 KB; feat (stride KP) aliases h (stride HSTR)

    const int tid = threadIdx.x;
    const int w = tid >> 6;
    const int lane = tid & 63;
    const int row_base = blockIdx.x * TILE_R;

    // ---- gather: wave w handles 16 nodes; lanes = 4 edge-slots x 16 feat-quads ----
    const int g  = lane >> 4;          // edge slot 0..3
    const int fo = (lane & 15) * 4;    // feature offset (float4)
    const f32x4 z4 = {0.0f, 0.0f, 0.0f, 0.0f};
    const f32x4 ninf4 = {-INFINITY, -INFINITY, -INFINITY, -INFINITY};

    for (int i = 0; i < 16; ++i) {
        const int rl = w * 16 + i;
        const int n = row_base + rl;
        short* frow = &smem[rl * KP];
        if (n < N_NODES) {
            const int s0    = (int)off[n];
            const int e_end = (n + 1 < N_NODES) ? (int)off[n + 1] : N_EDGES;
            const int deg   = e_end - s0;

            f32x4 sa = z4, sb = z4;
            f32x4 ma = ninf4, mb = ninf4;
            int p = s0 + g;
            for (; p + 4 < e_end; p += 8) {
                const int e0 = (int)perm[p];
                const int e1 = (int)perm[p + 4];
                const f32x4 v0 = *(const f32x4*)&ea[(size_t)e0 * EO + fo];
                const f32x4 v1 = *(const f32x4*)&ea[(size_t)e1 * EO + fo];
                sa += v0; ma = max4(ma, v0);
                sb += v1; mb = max4(mb, v1);
            }
            if (p < e_end) {
                const int e0 = (int)perm[p];
                const f32x4 v0 = *(const f32x4*)&ea[(size_t)e0 * EO + fo];
                sa += v0; ma = max4(ma, v0);
            }
            sa += sb; ma = max4(ma, mb);

            // butterfly across the 4 edge slots (xor 16, 32) -> all lanes full
            #pragma unroll
            for (int j = 0; j < 4; ++j) {
                float s = sa[j], m = ma[j];
                s += __shfl_xor(s, 16); m = fmaxf(m, __shfl_xor(m, 16));
                s += __shfl_xor(s, 32); m = fmaxf(m, __shfl_xor(m, 32));
                sa[j] = s; ma[j] = m;
            }

            const float rdeg = 1.0f / fmaxf((float)deg, 1.0f);
            if (g == 0) {
                #pragma unroll
                for (int j = 0; j < 4; ++j) frow[fo + j] = f2bf(sa[j]);
            } else if (g == 1) {
                #pragma unroll
                for (int j = 0; j < 4; ++j)
                    frow[EO + fo + j] = f2bf(deg > 0 ? ma[j] : 0.0f);
            } else if (g == 2) {
                #pragma unroll
                for (int j = 0; j < 4; ++j) frow[2 * EO + fo + j] = f2bf(sa[j] * rdeg);
            } else {
                const int c = (lane & 15) * 2;
                frow[192 + c]     = (c == 0) ? f2bf(u[batch[n]]) : (short)0;
                frow[192 + c + 1] = (short)0;
            }
        } else {
            frow[lane] = 0; frow[EO + lane] = 0; frow[2 * EO + lane] = 0;
            if (lane < 32) frow[192 + lane] = 0;
        }
    }
    __syncthreads();

    const int m = lane & 15, q = lane >> 4;
    const f32x4 vzero = {0.0f, 0.0f, 0.0f, 0.0f};

    // ---- GEMM1: 64 x 256, K=224; wave w owns cols [w*64, w*64+64) ----
    f32x4 acc1[4][4];
    #pragma unroll
    for (int a = 0; a < 4; ++a)
        #pragma unroll
        for (int b = 0; b < 4; ++b) acc1[a][b] = vzero;

    for (int kk = 0; kk < 7; ++kk) {
        const int k0 = kk * 32;
        bf16x8 afr[4];
        #pragma unroll
        for (int mt = 0; mt < 4; ++mt)
            afr[mt] = *(const bf16x8*)&smem[(mt * 16 + m) * KP + k0 + q * 8];
        #pragma unroll
        for (int ct = 0; ct < 4; ++ct) {
            const int col = w * 64 + ct * 16 + m;
            bf16x8 bfr = *(const bf16x8*)&W1T[col * KP + k0 + q * 8];
            #pragma unroll
            for (int mt = 0; mt < 4; ++mt)
                acc1[mt][ct] = __builtin_amdgcn_mfma_f32_16x16x32_bf16(afr[mt], bfr, acc1[mt][ct], 0, 0, 0);
        }
    }
    __syncthreads();   // feat fully consumed; smem becomes h

    // epilogue: bias + exact GELU -> h bf16 (stride HSTR)
    #pragma unroll
    for (int ct = 0; ct < 4; ++ct) {
        const int col = w * 64 + ct * 16 + m;
        const float bv = b1[col];
        #pragma unroll
        for (int mt = 0; mt < 4; ++mt) {
            #pragma unroll
            for (int i = 0; i < 4; ++i) {
                float t = acc1[mt][ct][i] + bv;
                t = 0.5f * t * (1.0f + erff(t * 0.70710678118654752f));
                smem[(mt * 16 + q * 4 + i) * HSTR + col] = f2bf(t);
            }
        }
    }
    __syncthreads();

    // ---- GEMM2: 64 x 128, K=256; wave w owns cols [w*32, w*32+32) ----
    f32x4 acc2[4][2];
    #pragma unroll
    for (int a = 0; a < 4; ++a) { acc2[a][0] = vzero; acc2[a][1] = vzero; }

    for (int kk = 0; kk < 8; ++kk) {
        const int k0 = kk * 32;
        bf16x8 afr[4];
        #pragma unroll
        for (int mt = 0; mt < 4; ++mt)
            afr[mt] = *(const bf16x8*)&smem[(mt * 16 + m) * HSTR + k0 + q * 8];
        #pragma unroll
        for (int ct = 0; ct < 2; ++ct) {
            const int col = w * 32 + ct * 16 + m;
            bf16x8 bfr = *(const bf16x8*)&W2T[col * HID + k0 + q * 8];
            #pragma unroll
            for (int mt = 0; mt < 4; ++mt)
                acc2[mt][ct] = __builtin_amdgcn_mfma_f32_16x16x32_bf16(afr[mt], bfr, acc2[mt][ct], 0, 0, 0);
        }
    }

    #pragma unroll
    for (int ct = 0; ct < 2; ++ct) {
        const int col = w * 32 + ct * 16 + m;
        const float bv = b2[col];
        #pragma unroll
        for (int mt = 0; mt < 4; ++mt) {
            #pragma unroll
            for (int i = 0; i < 4; ++i) {
                const int row = row_base + mt * 16 + q * 4 + i;
                if (row < N_NODES) out[(size_t)row * NOUT + col] = acc2[mt][ct][i] + bv;
            }
        }
    }
}

extern "C" void kernel_launch(void* const* d_in, const int* in_sizes, int n_in,
                              void* d_out, int out_size, void* d_ws, size_t ws_size,
                              hipStream_t stream) {
    // inputs: x, edge_index, edge_attr, u, batch, W1, b1, W2, b2
    const int*   ei    = (const int*)d_in[1];
    const float* ea    = (const float*)d_in[2];
    const float* u     = (const float*)d_in[3];
    const int*   batch = (const int*)d_in[4];
    const float* W1    = (const float*)d_in[5];
    const float* b1    = (const float*)d_in[6];
    const float* W2    = (const float*)d_in[7];
    const float* b2    = (const float*)d_in[8];
    float* out = (float*)d_out;

    unsigned* off    = (unsigned*)d_ws;          // N
    unsigned* cursor = off + N_NODES;            // N
    unsigned* perm   = cursor + N_NODES;         // E
    unsigned* bsum   = perm + N_EDGES;           // 512
    unsigned* boff   = bsum + 512;               // 512
    short*    W1T    = (short*)(boff + 512);     // 256*224 bf16
    short*    W2T    = W1T + HID * KP;           // 128*256 bf16

    const int NB = (N_NODES + 255) / 256;        // 391

    hipMemsetAsync(off, 0, (size_t)N_NODES * 4, stream);
    prep_k<<<(HID * KP + NOUT * HID + 255) / 256, 256, 0, stream>>>(W1, W2, W1T, W2T);
    hist_k<<<(N_EDGES + 255) / 256, 256, 0, stream>>>(ei, off);
    scan_part_k<<<NB, 256, 0, stream>>>(off, bsum);
    scan_top_k<<<1, 512, 0, stream>>>(bsum, boff, NB);
    scan_add_k<<<NB, 256, 0, stream>>>(off, boff, cursor);
    place_k<<<(N_EDGES + 255) / 256, 256, 0, stream>>>(ei, cursor, perm);
    fused_k<<<(N_NODES + TILE_R - 1) / TILE_R, 256, 0, stream>>>(
        off, perm, ea, u, batch, W1T, W2T, b1, b2, out);
}